// Round 12
// baseline (2211.473 us; speedup 1.0000x reference)
//
#include <hip/hip_runtime.h>

// ---------- types & helpers ----------
typedef __attribute__((ext_vector_type(8))) short sh8;   // 8 x bf16 (4 VGPRs)
typedef __attribute__((ext_vector_type(4))) float f4;    // MFMA accum / float4

__device__ __forceinline__ float bf2f(unsigned short u) {
    union { unsigned int u; float f; } c; c.u = ((unsigned int)u) << 16; return c.f;
}
__device__ __forceinline__ unsigned short f2bf(float f) {
    union { float f; unsigned int u; } c; c.f = f;
    unsigned int x = c.u;
    unsigned int r = (x + 0x7fffu + ((x >> 16) & 1u)) >> 16;   // RNE
    return (unsigned short)r;
}
__device__ __forceinline__ void bfsplit(float x, short& hi, short& lo) {
    unsigned short h = f2bf(x);
    float r = x - bf2f(h);
    hi = (short)h;
    lo = (short)f2bf(r);
}

#define CG_BLOCKS 1024   // fused count||gemm1: even bid = count, odd = gemm (round-11 verified)
#define CG_COUNT  512    // divisible by 8 -> fill reconstructs copy as (i>>8)&7
#define CSR_GRID  1568   // fill grid
#define OVL_AGG   1408   // producer blocks in agg||gemm overlap kernel
#define OVL_GEMM  384    // consumer blocks
#define FMAX      3200   // per-stage tile-flag capacity (>= ceil(N/32))

// ---------- INIT: zero counters+flags, pre-split W1..W3 (transposed, hi/lo bf16) ----------
// sp (shorts): Wh1@0 Wl1@16384 Wh2@32768 Wl2@49152 Wh3@65536 Wl3@81920
__global__ void k_init(int* cnt8, int M,
                       const float* __restrict__ W1, const float* __restrict__ W2,
                       const float* __restrict__ W3, unsigned short* __restrict__ sp,
                       int* __restrict__ flags) {
    int j = blockIdx.x * 256 + threadIdx.x;
    if (j < M) cnt8[j] = 0;
    if (j < 2 * FMAX) flags[j] = 0;
    if (j < 16384) {
        int k = j >> 7, col = j & 127;
        int t = col * 128 + k;
        short h, l;
        bfsplit(W1[j], h, l); sp[t] = (unsigned short)h; sp[16384 + t] = (unsigned short)l;
        bfsplit(W2[j], h, l); sp[32768 + t] = (unsigned short)h; sp[49152 + t] = (unsigned short)l;
        bfsplit(W3[j], h, l); sp[65536 + t] = (unsigned short)h; sp[81920 + t] = (unsigned short)l;
    }
}

// ---------- FUSED: degree count (+rank emit)  ||  layer-1 GEMM (unscaled) ----------
__device__ __forceinline__ void count_body(const int* __restrict__ dst,
                                           int* __restrict__ cnt8,
                                           int* __restrict__ rank, int E, int N) {
    int cidx = blockIdx.x >> 1;
    int base = (cidx & 7) * N;
    int E4 = E >> 2;
    for (int i = cidx * 256 + threadIdx.x; i < E4; i += CG_COUNT * 256) {
        int4 d = ((const int4*)dst)[i];
        int4 r;
        r.x = ((unsigned)d.x < (unsigned)N) ? atomicAdd(&cnt8[base + d.x], 1) : -1;
        r.y = ((unsigned)d.y < (unsigned)N) ? atomicAdd(&cnt8[base + d.y], 1) : -1;
        r.z = ((unsigned)d.z < (unsigned)N) ? atomicAdd(&cnt8[base + d.z], 1) : -1;
        r.w = ((unsigned)d.w < (unsigned)N) ? atomicAdd(&cnt8[base + d.w], 1) : -1;
        ((int4*)rank)[i] = r;
    }
    if (cidx == 0) {   // remainder edges -> copy 0
        for (int e = (E4 << 2) + threadIdx.x; e < E; e += 256) {
            int d = dst[e];
            rank[e] = ((unsigned)d < (unsigned)N) ? atomicAdd(&cnt8[d], 1) : -1;
        }
    }
}

// H[N][128](bf16) = X[N][128](fp32) @ W1 (unscaled; agg1 applies dis[src]).
__device__ __forceinline__ void gemm1_body(const float* __restrict__ X,
                                           const unsigned short* __restrict__ Wh,
                                           const unsigned short* __restrict__ Wl,
                                           unsigned short* __restrict__ H, int nPairs) {
    int gidx = blockIdx.x >> 1;
    int wave = threadIdx.x >> 6;
    int lane = threadIdx.x & 63;
    int ln = lane & 15, quad = lane >> 4;
    int c0 = (wave & 1) * 64;
    int subTile = wave >> 1;

    for (int p = gidx; p < nPairs; p += CG_COUNT) {
        int nodeBase = p * 32 + subTile * 16;
        const float* xrow = X + (nodeBase + ln) * 128 + quad * 8;
        sh8 ah[4], al[4];
        #pragma unroll
        for (int kt = 0; kt < 4; ++kt) {
            f4 v0 = *(const f4*)(xrow + kt * 32);
            f4 v1 = *(const f4*)(xrow + kt * 32 + 4);
            #pragma unroll
            for (int j = 0; j < 4; ++j) {
                short h, l;
                bfsplit(v0[j], h, l); ah[kt][j] = h; al[kt][j] = l;
                bfsplit(v1[j], h, l); ah[kt][j + 4] = h; al[kt][j + 4] = l;
            }
        }

        f4 acc[4] = { {0.f,0.f,0.f,0.f}, {0.f,0.f,0.f,0.f}, {0.f,0.f,0.f,0.f}, {0.f,0.f,0.f,0.f} };
        #pragma unroll
        for (int kt = 0; kt < 4; ++kt) {
            int k0 = kt * 32 + quad * 8;
            #pragma unroll
            for (int nt = 0; nt < 4; ++nt) {
                int col = c0 + nt * 16 + ln;
                sh8 bh = *(const sh8*)(Wh + col * 128 + k0);
                sh8 bl = *(const sh8*)(Wl + col * 128 + k0);
                acc[nt] = __builtin_amdgcn_mfma_f32_16x16x32_bf16(ah[kt], bh, acc[nt], 0, 0, 0);
                acc[nt] = __builtin_amdgcn_mfma_f32_16x16x32_bf16(ah[kt], bl, acc[nt], 0, 0, 0);
                acc[nt] = __builtin_amdgcn_mfma_f32_16x16x32_bf16(al[kt], bh, acc[nt], 0, 0, 0);
            }
        }

        #pragma unroll
        for (int nt = 0; nt < 4; ++nt) {
            int col = c0 + nt * 16 + ln;
            #pragma unroll
            for (int r = 0; r < 4; ++r)
                H[(nodeBase + quad * 4 + r) * 128 + col] = f2bf(acc[nt][r]);
        }
    }
}

__global__ __launch_bounds__(256)
void k_count_gemm1(const int* __restrict__ dst, int* __restrict__ cnt8,
                   int* __restrict__ rank, int E, int N,
                   const float* __restrict__ X,
                   const unsigned short* __restrict__ Wh,
                   const unsigned short* __restrict__ Wl,
                   unsigned short* __restrict__ H, int nPairs) {
    if ((blockIdx.x & 1) == 0)
        count_body(dst, cnt8, rank, E, N);
    else
        gemm1_body(X, Wh, Wl, H, nPairs);
}

#define SCAN_B 256
__global__ void k_scan_a(const int* __restrict__ cnt8, int* __restrict__ rowptr,
                         int* __restrict__ off8, int* __restrict__ deg,
                         int* __restrict__ bsum, float* __restrict__ dis, int N) {
    __shared__ int sh[SCAN_B];
    int t = threadIdx.x, i = blockIdx.x * SCAN_B + t;
    int c[8];
    int v = 0;
    if (i < N) {
        #pragma unroll
        for (int g = 0; g < 8; ++g) { c[g] = cnt8[g * N + i]; v += c[g]; }
        dis[i] = rsqrtf((float)(v + 1));   // +1 self loop
        deg[i] = v;
    }
    sh[t] = v; __syncthreads();
    for (int off = 1; off < SCAN_B; off <<= 1) {
        int x = (t >= off) ? sh[t - off] : 0;
        __syncthreads();
        sh[t] += x;
        __syncthreads();
    }
    int incl = sh[t];
    if (i < N) {
        int b = incl - v;
        rowptr[i] = b;
        int o = b;
        #pragma unroll
        for (int g = 0; g < 8; ++g) { off8[g * N + i] = o; o += c[g]; }
    }
    if (t == SCAN_B - 1) bsum[blockIdx.x] = incl;
}

__global__ void k_scan_b(int* bsum, int NB) {
    __shared__ int sh[512];
    int t = threadIdx.x;
    int v = (t < NB) ? bsum[t] : 0;
    sh[t] = v; __syncthreads();
    for (int off = 1; off < 512; off <<= 1) {
        int x = (t >= off) ? sh[t - off] : 0;
        __syncthreads();
        sh[t] += x;
        __syncthreads();
    }
    if (t < NB) bsum[t] = sh[t] - v;
}

__global__ void k_scan_c(int* __restrict__ rowptr, int* __restrict__ off8,
                         const int* __restrict__ bsum, int N) {
    int i = blockIdx.x * 256 + threadIdx.x;
    if (i < N) {
        int b = bsum[blockIdx.x];
        rowptr[i] += b;
        #pragma unroll
        for (int g = 0; g < 8; ++g) off8[g * N + i] += b;
    }
}

// ---------- Atomic-free CSR fill ----------
__global__ void k_fill(const int* __restrict__ src, const int* __restrict__ dst,
                       const int* __restrict__ rank, const int* __restrict__ off8,
                       int* __restrict__ csrc, int E, int N) {
    int E4 = E >> 2;
    for (int i = blockIdx.x * 256 + threadIdx.x; i < E4; i += gridDim.x * 256) {
        int g = (i >> 8) & 7;
        const int* off = off8 + g * N;
        int4 d4 = ((const int4*)dst)[i];
        int4 s4 = ((const int4*)src)[i];
        int4 r4 = ((const int4*)rank)[i];
        #pragma unroll
        for (int q = 0; q < 4; ++q) {
            int d = (q == 0) ? d4.x : (q == 1) ? d4.y : (q == 2) ? d4.z : d4.w;
            int s = (q == 0) ? s4.x : (q == 1) ? s4.y : (q == 2) ? s4.z : s4.w;
            int r = (q == 0) ? r4.x : (q == 1) ? r4.y : (q == 2) ? r4.z : r4.w;
            if ((unsigned)d >= (unsigned)N || (unsigned)s >= (unsigned)N || r < 0) continue;
            csrc[off[d] + r] = s;
        }
    }
    if (blockIdx.x == 0) {
        for (int e = (E4 << 2) + threadIdx.x; e < E; e += 256) {
            int d = dst[e];
            int s = src[e];
            int r = rank[e];
            if ((unsigned)d >= (unsigned)N || (unsigned)s >= (unsigned)N || r < 0) continue;
            csrc[off8[d] + r] = s;
        }
    }
}

// ---------- per-node aggregation body (HALF-WAVE: 2x16 lanes), round-11 numerics ----------
__device__ __forceinline__ void agg_one(const unsigned short* __restrict__ H,
                                        unsigned short* __restrict__ O,
                                        const float* __restrict__ dis,
                                        const int* __restrict__ rowptr,
                                        const int* __restrict__ deg,
                                        const int* __restrict__ csrc,
                                        const float* __restrict__ bias,
                                        int relu, int scaled, int n) {
    int lane = threadIdx.x & 31;
    int sub  = lane & 15;
    int half = lane >> 4;

    float a0 = 0.f, a1 = 0.f, a2 = 0.f, a3 = 0.f;
    float a4 = 0.f, a5 = 0.f, a6 = 0.f, a7 = 0.f;
    float dn = dis[n];

    auto addrow = [&](uint4 v) {
        a0 += bf2f((unsigned short)v.x);
        a1 += bf2f((unsigned short)(v.x >> 16));
        a2 += bf2f((unsigned short)v.y);
        a3 += bf2f((unsigned short)(v.y >> 16));
        a4 += bf2f((unsigned short)v.z);
        a5 += bf2f((unsigned short)(v.z >> 16));
        a6 += bf2f((unsigned short)v.w);
        a7 += bf2f((unsigned short)(v.w >> 16));
    };
    auto addroww = [&](uint4 v, float w) {
        a0 = fmaf(w, bf2f((unsigned short)v.x), a0);
        a1 = fmaf(w, bf2f((unsigned short)(v.x >> 16)), a1);
        a2 = fmaf(w, bf2f((unsigned short)v.y), a2);
        a3 = fmaf(w, bf2f((unsigned short)(v.y >> 16)), a3);
        a4 = fmaf(w, bf2f((unsigned short)v.z), a4);
        a5 = fmaf(w, bf2f((unsigned short)(v.z >> 16)), a5);
        a6 = fmaf(w, bf2f((unsigned short)v.w), a6);
        a7 = fmaf(w, bf2f((unsigned short)(v.w >> 16)), a7);
    };

    if (half == 0) {
        uint4 v = *(const uint4*)(H + (size_t)n * 128 + sub * 8);
        if (scaled) addrow(v); else addroww(v, dn);
    }

    int start = rowptr[n];
    int e = deg[n];
    int i = 0;
    if (scaled) {
        for (; i + 8 <= e; i += 8) {
            int s[4];
            #pragma unroll
            for (int q = 0; q < 4; ++q) s[q] = csrc[start + i + 2 * q + half];
            uint4 v[4];
            #pragma unroll
            for (int q = 0; q < 4; ++q) v[q] = *(const uint4*)(H + (size_t)s[q] * 128 + sub * 8);
            #pragma unroll
            for (int q = 0; q < 4; ++q) addrow(v[q]);
        }
        for (int j = i + half; j < e; j += 2) {
            int s = csrc[start + j];
            addrow(*(const uint4*)(H + (size_t)s * 128 + sub * 8));
        }
    } else {
        for (; i + 8 <= e; i += 8) {
            int s[4];
            #pragma unroll
            for (int q = 0; q < 4; ++q) s[q] = csrc[start + i + 2 * q + half];
            uint4 v[4];
            #pragma unroll
            for (int q = 0; q < 4; ++q) v[q] = *(const uint4*)(H + (size_t)s[q] * 128 + sub * 8);
            float w[4];
            #pragma unroll
            for (int q = 0; q < 4; ++q) w[q] = dis[s[q]];
            #pragma unroll
            for (int q = 0; q < 4; ++q) addroww(v[q], w[q]);
        }
        for (int j = i + half; j < e; j += 2) {
            int s = csrc[start + j];
            float w = dis[s];
            addroww(*(const uint4*)(H + (size_t)s * 128 + sub * 8), w);
        }
    }

    a0 += __shfl_xor(a0, 16); a1 += __shfl_xor(a1, 16);
    a2 += __shfl_xor(a2, 16); a3 += __shfl_xor(a3, 16);
    a4 += __shfl_xor(a4, 16); a5 += __shfl_xor(a5, 16);
    a6 += __shfl_xor(a6, 16); a7 += __shfl_xor(a7, 16);

    if (half == 0) {
        f4 b0 = *(const f4*)(bias + sub * 8);
        f4 b1 = *(const f4*)(bias + sub * 8 + 4);
        a0 = a0 * dn + b0[0]; a1 = a1 * dn + b0[1];
        a2 = a2 * dn + b0[2]; a3 = a3 * dn + b0[3];
        a4 = a4 * dn + b1[0]; a5 = a5 * dn + b1[1];
        a6 = a6 * dn + b1[2]; a7 = a7 * dn + b1[3];
        if (relu) {
            a0 = fmaxf(a0, 0.f); a1 = fmaxf(a1, 0.f);
            a2 = fmaxf(a2, 0.f); a3 = fmaxf(a3, 0.f);
            a4 = fmaxf(a4, 0.f); a5 = fmaxf(a5, 0.f);
            a6 = fmaxf(a6, 0.f); a7 = fmaxf(a7, 0.f);
        }
        uint4 ov;
        ov.x = (unsigned int)f2bf(a0) | ((unsigned int)f2bf(a1) << 16);
        ov.y = (unsigned int)f2bf(a2) | ((unsigned int)f2bf(a3) << 16);
        ov.z = (unsigned int)f2bf(a4) | ((unsigned int)f2bf(a5) << 16);
        ov.w = (unsigned int)f2bf(a6) | ((unsigned int)f2bf(a7) << 16);
        *(uint4*)(O + (size_t)n * 128 + sub * 8) = ov;
    }
}

// ---------- standalone aggregation (half-wave per node) ----------
__global__ __launch_bounds__(256)
void k_agg(const unsigned short* __restrict__ H, unsigned short* __restrict__ O,
           const float* __restrict__ dis, const int* __restrict__ rowptr,
           const int* __restrict__ deg, const int* __restrict__ csrc,
           const float* __restrict__ bias, int relu, int scaled, int N) {
    int n = (blockIdx.x * 256 + threadIdx.x) >> 5;
    if (n < N) agg_one(H, O, dis, rowptr, deg, csrc, bias, relu, scaled, n);
}

// ---------- OVERLAP: agg producer (per-tile flags) || next-layer GEMM consumer ----------
// Producer blocks [0,OVL_AGG): grid-stride 32-node tiles; 8 half-waves x 4 nodes;
// release = per-thread __threadfence + syncthreads + agent-scope flag store.
// Consumer blocks: spin on flag (relaxed agent load + s_sleep), one acquire fence,
// then the 32-row MFMA tile with L2-streamed split-W and *dis epilogue.
// Deadlock-free by construction: producers never wait.
__global__ __launch_bounds__(256)
void k_agg_gemm_ovl(const unsigned short* __restrict__ Hg,   // gather source
                    unsigned short* __restrict__ Ha,          // agg out
                    unsigned short* __restrict__ Ho,          // gemm out
                    const float* __restrict__ dis,
                    const int* __restrict__ rowptr, const int* __restrict__ deg,
                    const int* __restrict__ csrc, const float* __restrict__ bias,
                    int relu, int scaled,
                    const unsigned short* __restrict__ Wh,
                    const unsigned short* __restrict__ Wl,
                    int* __restrict__ flags, int N) {
    int nT = (N + 31) >> 5;
    if (blockIdx.x < OVL_AGG) {
        int hw = threadIdx.x >> 5;
        for (int tile = blockIdx.x; tile < nT; tile += OVL_AGG) {
            for (int k = 0; k < 4; ++k) {
                int n = tile * 32 + hw + 8 * k;
                if (n < N) agg_one(Hg, Ha, dis, rowptr, deg, csrc, bias, relu, scaled, n);
            }
            __threadfence();
            __syncthreads();
            if (threadIdx.x == 0)
                __hip_atomic_store(&flags[tile], 1, __ATOMIC_RELEASE, __HIP_MEMORY_SCOPE_AGENT);
        }
    } else {
        int wave = threadIdx.x >> 6;
        int lane = threadIdx.x & 63;
        int ln = lane & 15, quad = lane >> 4;
        int c0 = (wave & 1) * 64;
        int subTile = wave >> 1;
        for (int p = blockIdx.x - OVL_AGG; p < nT; p += OVL_GEMM) {
            while (__hip_atomic_load(&flags[p], __ATOMIC_RELAXED, __HIP_MEMORY_SCOPE_AGENT) == 0)
                __builtin_amdgcn_s_sleep(2);
            __threadfence();   // acquire: invalidate stale cache lines before reading Ha

            int nodeBase = p * 32 + subTile * 16;
            int arow = nodeBase + ln; if (arow >= N) arow = N - 1;
            const unsigned short* xrow = Ha + (size_t)arow * 128 + quad * 8;
            sh8 a[4];
            #pragma unroll
            for (int kt = 0; kt < 4; ++kt) a[kt] = *(const sh8*)(xrow + kt * 32);

            f4 acc[4] = { {0.f,0.f,0.f,0.f}, {0.f,0.f,0.f,0.f}, {0.f,0.f,0.f,0.f}, {0.f,0.f,0.f,0.f} };
            #pragma unroll
            for (int kt = 0; kt < 4; ++kt) {
                int k0 = kt * 32 + quad * 8;
                #pragma unroll
                for (int nt = 0; nt < 4; ++nt) {
                    int col = c0 + nt * 16 + ln;
                    sh8 bh = *(const sh8*)(Wh + col * 128 + k0);
                    sh8 bl = *(const sh8*)(Wl + col * 128 + k0);
                    acc[nt] = __builtin_amdgcn_mfma_f32_16x16x32_bf16(a[kt], bh, acc[nt], 0, 0, 0);
                    acc[nt] = __builtin_amdgcn_mfma_f32_16x16x32_bf16(a[kt], bl, acc[nt], 0, 0, 0);
                }
            }

            int orow0 = nodeBase + quad * 4;
            float ds[4];
            #pragma unroll
            for (int r = 0; r < 4; ++r) ds[r] = (orow0 + r < N) ? dis[orow0 + r] : 0.f;
            #pragma unroll
            for (int nt = 0; nt < 4; ++nt) {
                int col = c0 + nt * 16 + ln;
                #pragma unroll
                for (int r = 0; r < 4; ++r)
                    if (orow0 + r < N)
                        Ho[(size_t)(orow0 + r) * 128 + col] = f2bf(acc[nt][r] * ds[r]);
            }
        }
    }
}

// ---------- GEMM (serial fallback, layers 2,3): reg-cached split W ----------
__global__ __launch_bounds__(256)
void k_gemm128_a16(const unsigned short* __restrict__ X,
                   const float* __restrict__ W,
                   const float* __restrict__ dis,
                   unsigned short* __restrict__ H, int nPairs) {
    int wave = threadIdx.x >> 6;
    int lane = threadIdx.x & 63;
    int ln = lane & 15, quad = lane >> 4;
    int c0 = (wave & 1) * 64;
    int subTile = wave >> 1;

    sh8 bh[4][4], blo[4][4];
    #pragma unroll
    for (int nt = 0; nt < 4; ++nt) {
        int col = c0 + nt * 16 + ln;
        #pragma unroll
        for (int kt = 0; kt < 4; ++kt) {
            int k0 = kt * 32 + quad * 8;
            #pragma unroll
            for (int j = 0; j < 8; ++j) {
                short h, l;
                bfsplit(W[(k0 + j) * 128 + col], h, l);
                bh[nt][kt][j] = h; blo[nt][kt][j] = l;
            }
        }
    }

    for (int p = blockIdx.x; p < nPairs; p += gridDim.x) {
        int nodeBase = p * 32 + subTile * 16;
        const unsigned short* xrow = X + (nodeBase + ln) * 128 + quad * 8;
        sh8 a[4];
        #pragma unroll
        for (int kt = 0; kt < 4; ++kt) a[kt] = *(const sh8*)(xrow + kt * 32);

        f4 acc[4] = { {0.f,0.f,0.f,0.f}, {0.f,0.f,0.f,0.f}, {0.f,0.f,0.f,0.f}, {0.f,0.f,0.f,0.f} };
        #pragma unroll
        for (int kt = 0; kt < 4; ++kt)
            #pragma unroll
            for (int nt = 0; nt < 4; ++nt) {
                acc[nt] = __builtin_amdgcn_mfma_f32_16x16x32_bf16(a[kt], bh[nt][kt], acc[nt], 0, 0, 0);
                acc[nt] = __builtin_amdgcn_mfma_f32_16x16x32_bf16(a[kt], blo[nt][kt], acc[nt], 0, 0, 0);
            }

        float ds[4];
        #pragma unroll
        for (int r = 0; r < 4; ++r) ds[r] = dis[nodeBase + quad * 4 + r];
        #pragma unroll
        for (int nt = 0; nt < 4; ++nt) {
            int col = c0 + nt * 16 + ln;
            #pragma unroll
            for (int r = 0; r < 4; ++r)
                H[(nodeBase + quad * 4 + r) * 128 + col] = f2bf(acc[nt][r] * ds[r]);
        }
    }
}

// ---------- Final head: OUT[N][40](fp32) = X(bf16) @ Wl(fp32 split) + bl ----------
__global__ __launch_bounds__(256)
void k_gemm_final(const unsigned short* __restrict__ X,
                  const float* __restrict__ W,     // [128][40]
                  const float* __restrict__ bl,    // [40]
                  float* __restrict__ OUT, int nTiles) {
    int wave = threadIdx.x >> 6;
    int lane = threadIdx.x & 63;
    int ln = lane & 15, quad = lane >> 4;
    int tile = blockIdx.x * 4 + wave;
    if (tile >= nTiles) return;

    sh8 bh[3][4], blo[3][4];
    #pragma unroll
    for (int nt = 0; nt < 3; ++nt) {
        int col = nt * 16 + ln;
        bool valid = (col < 40);
        #pragma unroll
        for (int kt = 0; kt < 4; ++kt) {
            int k0 = kt * 32 + quad * 8;
            #pragma unroll
            for (int j = 0; j < 8; ++j) {
                short h = 0, l = 0;
                if (valid) bfsplit(W[(k0 + j) * 40 + col], h, l);
                bh[nt][kt][j] = h; blo[nt][kt][j] = l;
            }
        }
    }

    int nodeBase = tile * 16;
    const unsigned short* xrow = X + (nodeBase + ln) * 128 + quad * 8;
    sh8 a[4];
    #pragma unroll
    for (int kt = 0; kt < 4; ++kt) a[kt] = *(const sh8*)(xrow + kt * 32);

    f4 acc[3] = { {0.f,0.f,0.f,0.f}, {0.f,0.f,0.f,0.f}, {0.f,0.f,0.f,0.f} };
    #pragma unroll
    for (int kt = 0; kt < 4; ++kt)
        #pragma unroll
        for (int nt = 0; nt < 3; ++nt) {
            acc[nt] = __builtin_amdgcn_mfma_f32_16x16x32_bf16(a[kt], bh[nt][kt], acc[nt], 0, 0, 0);
            acc[nt] = __builtin_amdgcn_mfma_f32_16x16x32_bf16(a[kt], blo[nt][kt], acc[nt], 0, 0, 0);
        }

    #pragma unroll
    for (int nt = 0; nt < 3; ++nt) {
        int col = nt * 16 + ln;
        if (col < 40) {
            float bv = bl[col];
            #pragma unroll
            for (int r = 0; r < 4; ++r)
                OUT[(nodeBase + quad * 4 + r) * 40 + col] = acc[nt][r] + bv;
        }
    }
}

// ---------- launch ----------
extern "C" void kernel_launch(void* const* d_in, const int* in_sizes, int n_in,
                              void* d_out, int out_size, void* d_ws, size_t ws_size,
                              hipStream_t stream) {
    const float* x  = (const float*)d_in[0];
    const int*   ei = (const int*)d_in[1];
    const float* W1 = (const float*)d_in[2];
    const float* b1 = (const float*)d_in[3];
    const float* W2 = (const float*)d_in[4];
    const float* b2 = (const float*)d_in[5];
    const float* W3 = (const float*)d_in[6];
    const float* b3 = (const float*)d_in[7];
    const float* Wl = (const float*)d_in[8];
    const float* bl = (const float*)d_in[9];

    const int N = in_sizes[0] / 128;   // 100000
    const int E = in_sizes[1] / 2;     // 1600000
    const int* srcIdx = ei;
    const int* dstIdx = ei + E;

    char* ws = (char*)d_ws;
    size_t off = 0;
    auto alloc = [&](size_t bytes) { void* p = ws + off; off += (bytes + 511) & ~(size_t)511; return p; };
    int*   rowptr  = (int*)  alloc((size_t)N * 4);
    int*   deg     = (int*)  alloc((size_t)N * 4);
    float* dis     = (float*)alloc((size_t)N * 4);
    int*   bsum    = (int*)  alloc(512 * 4);
    unsigned short* wsp = (unsigned short*)alloc(6 * 16384 * 2);   // split W1..W3 hi/lo
    int*   flags   = (int*)  alloc(2 * FMAX * 4);                  // per-tile ready flags
    int*   csrc    = (int*)  alloc((size_t)E * 4);
    unsigned short* h0 = (unsigned short*)alloc((size_t)N * 128 * 2);
    unsigned short* h1 = (unsigned short*)alloc((size_t)N * 128 * 2);
    size_t off_no_h2 = off;
    unsigned short* h2 = (unsigned short*)alloc((size_t)N * 128 * 2);
    bool fused = (ws_size >= off);           // h2 fits -> overlap path
    (void)off_no_h2;

    // Aliases live in h1 (h0 is written CONCURRENTLY by fused gemm1); all consumed
    // by scan/fill before anything writes h1:
    int* rank = (int*)h1;
    int* off8 = (int*)((char*)h1 + (8u << 20));
    int* cnt8 = (int*)((char*)h1 + (16u << 20));
    unsigned short* Wh1 = wsp;
    unsigned short* Wl1 = wsp + 16384;
    unsigned short* Wh2 = wsp + 32768;
    unsigned short* Wl2 = wsp + 49152;
    unsigned short* Wh3 = wsp + 65536;
    unsigned short* Wl3 = wsp + 81920;

    const int gN = (N + 255) / 256;           // 391
    const int nPairs = N / 32;                // 3125
    const int nTiles = N / 16;                // 6250
    const int gAgg = (N * 32 + 255) / 256;    // 12500 (half-wave per node)
    const int gZ8 = (N * 8 + 255) / 256;

    // Init, fused(count || gemm1), scans, atomic-free fill
    k_init<<<gZ8, 256, 0, stream>>>(cnt8, N * 8, W1, W2, W3, wsp, flags);
    k_count_gemm1<<<CG_BLOCKS, 256, 0, stream>>>(dstIdx, cnt8, rank, E, N,
                                                 x, Wh1, Wl1, h0, nPairs);
    k_scan_a<<<gN, 256, 0, stream>>>(cnt8, rowptr, off8, deg, bsum, dis, N);
    k_scan_b<<<1, 512, 0, stream>>>(bsum, gN);
    k_scan_c<<<gN, 256, 0, stream>>>(rowptr, off8, bsum, N);
    k_fill<<<CSR_GRID, 256, 0, stream>>>(srcIdx, dstIdx, rank, off8, csrc, E, N);

    if (fused) {
        // agg1(h0) || gemm2 -> h1(agg out), h2(gemm out, pre-scaled)
        k_agg_gemm_ovl<<<OVL_AGG + OVL_GEMM, 256, 0, stream>>>(
            h0, h1, h2, dis, rowptr, deg, csrc, b1, 1, 0, Wh2, Wl2, flags, N);
        // agg2(h2) || gemm3 -> h0(agg out), h1(gemm out, pre-scaled)
        k_agg_gemm_ovl<<<OVL_AGG + OVL_GEMM, 256, 0, stream>>>(
            h2, h0, h1, dis, rowptr, deg, csrc, b2, 1, 1, Wh3, Wl3, flags + FMAX, N);
        // agg3 (pre-scaled, no relu) -> h0; head -> OUT
        k_agg<<<gAgg, 256, 0, stream>>>(h1, h0, dis, rowptr, deg, csrc, b3, 0, 1, N);
        k_gemm_final<<<(nTiles + 3) / 4, 256, 0, stream>>>(h0, Wl, bl, (float*)d_out, nTiles);
    } else {
        // serial fallback (round-11 path, verified 471us)
        k_agg<<<gAgg, 256, 0, stream>>>(h0, h1, dis, rowptr, deg, csrc, b1, 1, 0, N);
        k_gemm128_a16<<<768, 256, 0, stream>>>(h1, W2, dis, h0, nPairs);
        k_agg<<<gAgg, 256, 0, stream>>>(h0, h1, dis, rowptr, deg, csrc, b2, 1, 1, N);
        k_gemm128_a16<<<768, 256, 0, stream>>>(h1, W3, dis, h0, nPairs);
        k_agg<<<gAgg, 256, 0, stream>>>(h0, h1, dis, rowptr, deg, csrc, b3, 0, 1, N);
        k_gemm_final<<<(nTiles + 3) / 4, 256, 0, stream>>>(h1, Wl, bl, (float*)d_out, nTiles);
    }
}

// Round 13
// 469.827 us; speedup vs baseline: 4.7070x; 4.7070x over previous
//
#include <hip/hip_runtime.h>

// ---------- types & helpers ----------
typedef __attribute__((ext_vector_type(8))) short sh8;   // 8 x bf16 (4 VGPRs)
typedef __attribute__((ext_vector_type(4))) float f4;    // MFMA accum / float4

__device__ __forceinline__ float bf2f(unsigned short u) {
    union { unsigned int u; float f; } c; c.u = ((unsigned int)u) << 16; return c.f;
}
__device__ __forceinline__ unsigned short f2bf(float f) {
    union { float f; unsigned int u; } c; c.f = f;
    unsigned int x = c.u;
    unsigned int r = (x + 0x7fffu + ((x >> 16) & 1u)) >> 16;   // RNE
    return (unsigned short)r;
}
__device__ __forceinline__ void bfsplit(float x, short& hi, short& lo) {
    unsigned short h = f2bf(x);
    float r = x - bf2f(h);
    hi = (short)h;
    lo = (short)f2bf(r);
}

// Fused count||gemm1 sized to EXACT residency (round-11 verified: 87->76us).
#define CG_BLOCKS 1024   // even bid = count (512), odd bid = gemm (512)
#define CG_COUNT  512    // divisible by 8 -> fill reconstructs copy as (i>>8)&7
#define CSR_GRID  1568   // fill grid

// ---------- INIT: zero shadow counters + pre-split W1 (transposed, hi/lo bf16) ----------
// Only the FUSED gemm1 streams W from L2 (low VGPR -> co-residency with count).
// Standalone layer-2/3 GEMMs keep register-cached W (round-8 lesson).
__global__ void k_init(int* cnt8, int M,
                       const float* __restrict__ W1, unsigned short* __restrict__ sp) {
    int j = blockIdx.x * 256 + threadIdx.x;
    if (j < M) cnt8[j] = 0;
    if (j < 16384) {
        int k = j >> 7, col = j & 127;
        int t = col * 128 + k;
        short h, l;
        bfsplit(W1[j], h, l);
        sp[t] = (unsigned short)h;
        sp[16384 + t] = (unsigned short)l;
    }
}

// ---------- FUSED: degree count (+rank emit)  ||  layer-1 GEMM (unscaled) ----------
__device__ __forceinline__ void count_body(const int* __restrict__ dst,
                                           int* __restrict__ cnt8,
                                           int* __restrict__ rank, int E, int N) {
    int cidx = blockIdx.x >> 1;
    int base = (cidx & 7) * N;
    int E4 = E >> 2;
    for (int i = cidx * 256 + threadIdx.x; i < E4; i += CG_COUNT * 256) {
        int4 d = ((const int4*)dst)[i];
        int4 r;
        r.x = ((unsigned)d.x < (unsigned)N) ? atomicAdd(&cnt8[base + d.x], 1) : -1;
        r.y = ((unsigned)d.y < (unsigned)N) ? atomicAdd(&cnt8[base + d.y], 1) : -1;
        r.z = ((unsigned)d.z < (unsigned)N) ? atomicAdd(&cnt8[base + d.z], 1) : -1;
        r.w = ((unsigned)d.w < (unsigned)N) ? atomicAdd(&cnt8[base + d.w], 1) : -1;
        ((int4*)rank)[i] = r;
    }
    if (cidx == 0) {   // remainder edges -> copy 0
        for (int e = (E4 << 2) + threadIdx.x; e < E; e += 256) {
            int d = dst[e];
            rank[e] = ((unsigned)d < (unsigned)N) ? atomicAdd(&cnt8[d], 1) : -1;
        }
    }
}

// H[N][128](bf16) = X[N][128](fp32) @ W1 (unscaled; agg1 applies dis[src]).
// B-fragments streamed from pre-split L2 tables -> low VGPR -> high co-residency.
__device__ __forceinline__ void gemm1_body(const float* __restrict__ X,
                                           const unsigned short* __restrict__ Wh,
                                           const unsigned short* __restrict__ Wl,
                                           unsigned short* __restrict__ H, int nPairs) {
    int gidx = blockIdx.x >> 1;
    int wave = threadIdx.x >> 6;
    int lane = threadIdx.x & 63;
    int ln = lane & 15, quad = lane >> 4;
    int c0 = (wave & 1) * 64;
    int subTile = wave >> 1;

    for (int p = gidx; p < nPairs; p += CG_COUNT) {
        int nodeBase = p * 32 + subTile * 16;
        const float* xrow = X + (nodeBase + ln) * 128 + quad * 8;
        sh8 ah[4], al[4];
        #pragma unroll
        for (int kt = 0; kt < 4; ++kt) {
            f4 v0 = *(const f4*)(xrow + kt * 32);
            f4 v1 = *(const f4*)(xrow + kt * 32 + 4);
            #pragma unroll
            for (int j = 0; j < 4; ++j) {
                short h, l;
                bfsplit(v0[j], h, l); ah[kt][j] = h; al[kt][j] = l;
                bfsplit(v1[j], h, l); ah[kt][j + 4] = h; al[kt][j + 4] = l;
            }
        }

        f4 acc[4] = { {0.f,0.f,0.f,0.f}, {0.f,0.f,0.f,0.f}, {0.f,0.f,0.f,0.f}, {0.f,0.f,0.f,0.f} };
        #pragma unroll
        for (int kt = 0; kt < 4; ++kt) {
            int k0 = kt * 32 + quad * 8;
            #pragma unroll
            for (int nt = 0; nt < 4; ++nt) {
                int col = c0 + nt * 16 + ln;
                sh8 bh = *(const sh8*)(Wh + col * 128 + k0);
                sh8 bl = *(const sh8*)(Wl + col * 128 + k0);
                acc[nt] = __builtin_amdgcn_mfma_f32_16x16x32_bf16(ah[kt], bh, acc[nt], 0, 0, 0);
                acc[nt] = __builtin_amdgcn_mfma_f32_16x16x32_bf16(ah[kt], bl, acc[nt], 0, 0, 0);
                acc[nt] = __builtin_amdgcn_mfma_f32_16x16x32_bf16(al[kt], bh, acc[nt], 0, 0, 0);
            }
        }

        #pragma unroll
        for (int nt = 0; nt < 4; ++nt) {
            int col = c0 + nt * 16 + ln;
            #pragma unroll
            for (int r = 0; r < 4; ++r)
                H[(nodeBase + quad * 4 + r) * 128 + col] = f2bf(acc[nt][r]);
        }
    }
}

__global__ __launch_bounds__(256)
void k_count_gemm1(const int* __restrict__ dst, int* __restrict__ cnt8,
                   int* __restrict__ rank, int E, int N,
                   const float* __restrict__ X,
                   const unsigned short* __restrict__ Wh,
                   const unsigned short* __restrict__ Wl,
                   unsigned short* __restrict__ H, int nPairs) {
    if ((blockIdx.x & 1) == 0)
        count_body(dst, cnt8, rank, E, N);
    else
        gemm1_body(X, Wh, Wl, H, nPairs);
}

#define SCAN_B 256
__global__ void k_scan_a(const int* __restrict__ cnt8, int* __restrict__ rowptr,
                         int* __restrict__ off8, int* __restrict__ deg,
                         int* __restrict__ bsum, float* __restrict__ dis, int N) {
    __shared__ int sh[SCAN_B];
    int t = threadIdx.x, i = blockIdx.x * SCAN_B + t;
    int c[8];
    int v = 0;
    if (i < N) {
        #pragma unroll
        for (int g = 0; g < 8; ++g) { c[g] = cnt8[g * N + i]; v += c[g]; }
        dis[i] = rsqrtf((float)(v + 1));   // +1 self loop
        deg[i] = v;
    }
    sh[t] = v; __syncthreads();
    for (int off = 1; off < SCAN_B; off <<= 1) {
        int x = (t >= off) ? sh[t - off] : 0;
        __syncthreads();
        sh[t] += x;
        __syncthreads();
    }
    int incl = sh[t];
    if (i < N) {
        int b = incl - v;
        rowptr[i] = b;
        int o = b;
        #pragma unroll
        for (int g = 0; g < 8; ++g) { off8[g * N + i] = o; o += c[g]; }
    }
    if (t == SCAN_B - 1) bsum[blockIdx.x] = incl;
}

__global__ void k_scan_b(int* bsum, int NB) {
    __shared__ int sh[512];
    int t = threadIdx.x;
    int v = (t < NB) ? bsum[t] : 0;
    sh[t] = v; __syncthreads();
    for (int off = 1; off < 512; off <<= 1) {
        int x = (t >= off) ? sh[t - off] : 0;
        __syncthreads();
        sh[t] += x;
        __syncthreads();
    }
    if (t < NB) bsum[t] = sh[t] - v;
}

__global__ void k_scan_c(int* __restrict__ rowptr, int* __restrict__ off8,
                         const int* __restrict__ bsum, int N) {
    int i = blockIdx.x * 256 + threadIdx.x;
    if (i < N) {
        int b = bsum[blockIdx.x];
        rowptr[i] += b;
        #pragma unroll
        for (int g = 0; g < 8; ++g) off8[g * N + i] += b;
    }
}

// ---------- Atomic-free CSR fill ----------
// csrc[off8[g][d] + rank[e]] = src[e]; g = (i>>8)&7 (count grid 512 ≡ 0 mod 8).
__global__ void k_fill(const int* __restrict__ src, const int* __restrict__ dst,
                       const int* __restrict__ rank, const int* __restrict__ off8,
                       int* __restrict__ csrc, int E, int N) {
    int E4 = E >> 2;
    for (int i = blockIdx.x * 256 + threadIdx.x; i < E4; i += gridDim.x * 256) {
        int g = (i >> 8) & 7;
        const int* off = off8 + g * N;
        int4 d4 = ((const int4*)dst)[i];
        int4 s4 = ((const int4*)src)[i];
        int4 r4 = ((const int4*)rank)[i];
        #pragma unroll
        for (int q = 0; q < 4; ++q) {
            int d = (q == 0) ? d4.x : (q == 1) ? d4.y : (q == 2) ? d4.z : d4.w;
            int s = (q == 0) ? s4.x : (q == 1) ? s4.y : (q == 2) ? s4.z : s4.w;
            int r = (q == 0) ? r4.x : (q == 1) ? r4.y : (q == 2) ? r4.z : r4.w;
            if ((unsigned)d >= (unsigned)N || (unsigned)s >= (unsigned)N || r < 0) continue;
            csrc[off[d] + r] = s;
        }
    }
    if (blockIdx.x == 0) {   // remainder edges -> copy 0
        for (int e = (E4 << 2) + threadIdx.x; e < E; e += 256) {
            int d = dst[e];
            int s = src[e];
            int r = rank[e];
            if ((unsigned)d >= (unsigned)N || (unsigned)s >= (unsigned)N || r < 0) continue;
            csrc[off8[d] + r] = s;
        }
    }
}

// ---------- GEMM (layers 2,3): H(bf16) = (X(bf16) @ W(fp32, split, reg-cached)) * dis[row] ----------
// 1-deep A-fragment prefetch: next tile's 4 b128 loads issue BEFORE this tile's
// MFMA block (latency-bound at 3 waves/SIMD; compiler doesn't pipeline across the
// grid-stride loop). +16 VGPR (136->~152), still 3 waves/SIMD.
__global__ __launch_bounds__(256)
void k_gemm128_a16(const unsigned short* __restrict__ X,
                   const float* __restrict__ W,
                   const float* __restrict__ dis,
                   unsigned short* __restrict__ H, int nPairs) {
    int wave = threadIdx.x >> 6;
    int lane = threadIdx.x & 63;
    int ln = lane & 15, quad = lane >> 4;
    int c0 = (wave & 1) * 64;
    int subTile = wave >> 1;

    sh8 bh[4][4], blo[4][4];
    #pragma unroll
    for (int nt = 0; nt < 4; ++nt) {
        int col = c0 + nt * 16 + ln;
        #pragma unroll
        for (int kt = 0; kt < 4; ++kt) {
            int k0 = kt * 32 + quad * 8;
            #pragma unroll
            for (int j = 0; j < 8; ++j) {
                short h, l;
                bfsplit(W[(k0 + j) * 128 + col], h, l);
                bh[nt][kt][j] = h; blo[nt][kt][j] = l;
            }
        }
    }

    int p = blockIdx.x;
    sh8 a[4];
    if (p < nPairs) {
        const unsigned short* xrow = X + ((size_t)(p * 32 + subTile * 16 + ln)) * 128 + quad * 8;
        #pragma unroll
        for (int kt = 0; kt < 4; ++kt) a[kt] = *(const sh8*)(xrow + kt * 32);
    }
    while (p < nPairs) {
        int pn = p + (int)gridDim.x;
        sh8 an[4];
        if (pn < nPairs) {   // prefetch next tile's A before current MFMAs
            const unsigned short* xn = X + ((size_t)(pn * 32 + subTile * 16 + ln)) * 128 + quad * 8;
            #pragma unroll
            for (int kt = 0; kt < 4; ++kt) an[kt] = *(const sh8*)(xn + kt * 32);
        }

        f4 acc[4] = { {0.f,0.f,0.f,0.f}, {0.f,0.f,0.f,0.f}, {0.f,0.f,0.f,0.f}, {0.f,0.f,0.f,0.f} };
        #pragma unroll
        for (int kt = 0; kt < 4; ++kt)
            #pragma unroll
            for (int nt = 0; nt < 4; ++nt) {
                acc[nt] = __builtin_amdgcn_mfma_f32_16x16x32_bf16(a[kt], bh[nt][kt], acc[nt], 0, 0, 0);
                acc[nt] = __builtin_amdgcn_mfma_f32_16x16x32_bf16(a[kt], blo[nt][kt], acc[nt], 0, 0, 0);
            }

        int nodeBase = p * 32 + subTile * 16;
        float ds[4];
        #pragma unroll
        for (int r = 0; r < 4; ++r) ds[r] = dis[nodeBase + quad * 4 + r];
        #pragma unroll
        for (int nt = 0; nt < 4; ++nt) {
            int col = c0 + nt * 16 + ln;
            #pragma unroll
            for (int r = 0; r < 4; ++r)
                H[(nodeBase + quad * 4 + r) * 128 + col] = f2bf(acc[nt][r] * ds[r]);
        }

        #pragma unroll
        for (int kt = 0; kt < 4; ++kt) a[kt] = an[kt];
        p = pn;
    }
}

// ---------- Aggregation: one HALF-WAVE (2 x 16 lanes) per node ----------
// scaled=1: H rows pre-scaled by dis[src] (layers 2,3); scaled=0: raw H (layer 1).
__global__ __launch_bounds__(256)
void k_agg(const unsigned short* __restrict__ H,
           unsigned short* __restrict__ O,
           const float* __restrict__ dis,
           const int* __restrict__ rowptr,
           const int* __restrict__ deg,
           const int* __restrict__ csrc,
           const float* __restrict__ bias,
           int relu, int scaled, int N) {
    int n = (blockIdx.x * 256 + threadIdx.x) >> 5;
    if (n >= N) return;
    int lane = threadIdx.x & 31;
    int sub  = lane & 15;      // feats sub*8 .. sub*8+7 (16B)
    int half = lane >> 4;      // which edge of each pair

    float a0 = 0.f, a1 = 0.f, a2 = 0.f, a3 = 0.f;
    float a4 = 0.f, a5 = 0.f, a6 = 0.f, a7 = 0.f;
    float dn = dis[n];

    auto addrow = [&](uint4 v) {
        a0 += bf2f((unsigned short)v.x);
        a1 += bf2f((unsigned short)(v.x >> 16));
        a2 += bf2f((unsigned short)v.y);
        a3 += bf2f((unsigned short)(v.y >> 16));
        a4 += bf2f((unsigned short)v.z);
        a5 += bf2f((unsigned short)(v.z >> 16));
        a6 += bf2f((unsigned short)v.w);
        a7 += bf2f((unsigned short)(v.w >> 16));
    };
    auto addroww = [&](uint4 v, float w) {
        a0 = fmaf(w, bf2f((unsigned short)v.x), a0);
        a1 = fmaf(w, bf2f((unsigned short)(v.x >> 16)), a1);
        a2 = fmaf(w, bf2f((unsigned short)v.y), a2);
        a3 = fmaf(w, bf2f((unsigned short)(v.y >> 16)), a3);
        a4 = fmaf(w, bf2f((unsigned short)v.z), a4);
        a5 = fmaf(w, bf2f((unsigned short)(v.z >> 16)), a5);
        a6 = fmaf(w, bf2f((unsigned short)v.w), a6);
        a7 = fmaf(w, bf2f((unsigned short)(v.w >> 16)), a7);
    };

    if (half == 0) {   // self loop (final *dn gives dn^2 weight)
        uint4 v = *(const uint4*)(H + (size_t)n * 128 + sub * 8);
        if (scaled) addrow(v); else addroww(v, dn);
    }

    int start = rowptr[n];
    int e = deg[n];
    int i = 0;
    if (scaled) {
        for (; i + 8 <= e; i += 8) {     // 8 edges per round, 4 per 16-lane group
            int s[4];
            #pragma unroll
            for (int q = 0; q < 4; ++q) s[q] = csrc[start + i + 2 * q + half];
            uint4 v[4];
            #pragma unroll
            for (int q = 0; q < 4; ++q) v[q] = *(const uint4*)(H + (size_t)s[q] * 128 + sub * 8);
            #pragma unroll
            for (int q = 0; q < 4; ++q) addrow(v[q]);
        }
        for (int j = i + half; j < e; j += 2) {
            int s = csrc[start + j];
            addrow(*(const uint4*)(H + (size_t)s * 128 + sub * 8));
        }
    } else {
        for (; i + 8 <= e; i += 8) {
            int s[4];
            #pragma unroll
            for (int q = 0; q < 4; ++q) s[q] = csrc[start + i + 2 * q + half];
            uint4 v[4];
            #pragma unroll
            for (int q = 0; q < 4; ++q) v[q] = *(const uint4*)(H + (size_t)s[q] * 128 + sub * 8);
            float w[4];
            #pragma unroll
            for (int q = 0; q < 4; ++q) w[q] = dis[s[q]];
            #pragma unroll
            for (int q = 0; q < 4; ++q) addroww(v[q], w[q]);
        }
        for (int j = i + half; j < e; j += 2) {
            int s = csrc[start + j];
            float w = dis[s];
            addroww(*(const uint4*)(H + (size_t)s * 128 + sub * 8), w);
        }
    }

    a0 += __shfl_xor(a0, 16); a1 += __shfl_xor(a1, 16);
    a2 += __shfl_xor(a2, 16); a3 += __shfl_xor(a3, 16);
    a4 += __shfl_xor(a4, 16); a5 += __shfl_xor(a5, 16);
    a6 += __shfl_xor(a6, 16); a7 += __shfl_xor(a7, 16);

    if (half == 0) {
        f4 b0 = *(const f4*)(bias + sub * 8);
        f4 b1 = *(const f4*)(bias + sub * 8 + 4);
        a0 = a0 * dn + b0[0]; a1 = a1 * dn + b0[1];
        a2 = a2 * dn + b0[2]; a3 = a3 * dn + b0[3];
        a4 = a4 * dn + b1[0]; a5 = a5 * dn + b1[1];
        a6 = a6 * dn + b1[2]; a7 = a7 * dn + b1[3];
        if (relu) {
            a0 = fmaxf(a0, 0.f); a1 = fmaxf(a1, 0.f);
            a2 = fmaxf(a2, 0.f); a3 = fmaxf(a3, 0.f);
            a4 = fmaxf(a4, 0.f); a5 = fmaxf(a5, 0.f);
            a6 = fmaxf(a6, 0.f); a7 = fmaxf(a7, 0.f);
        }
        uint4 ov;
        ov.x = (unsigned int)f2bf(a0) | ((unsigned int)f2bf(a1) << 16);
        ov.y = (unsigned int)f2bf(a2) | ((unsigned int)f2bf(a3) << 16);
        ov.z = (unsigned int)f2bf(a4) | ((unsigned int)f2bf(a5) << 16);
        ov.w = (unsigned int)f2bf(a6) | ((unsigned int)f2bf(a7) << 16);
        *(uint4*)(O + (size_t)n * 128 + sub * 8) = ov;
    }
}

// ---------- Final head: OUT[N][40](fp32) = X(bf16) @ Wl(fp32 split) + bl ----------
__global__ __launch_bounds__(256)
void k_gemm_final(const unsigned short* __restrict__ X,
                  const float* __restrict__ W,     // [128][40]
                  const float* __restrict__ bl,    // [40]
                  float* __restrict__ OUT, int nTiles) {
    int wave = threadIdx.x >> 6;
    int lane = threadIdx.x & 63;
    int ln = lane & 15, quad = lane >> 4;
    int tile = blockIdx.x * 4 + wave;
    if (tile >= nTiles) return;

    sh8 bh[3][4], blo[3][4];
    #pragma unroll
    for (int nt = 0; nt < 3; ++nt) {
        int col = nt * 16 + ln;
        bool valid = (col < 40);
        #pragma unroll
        for (int kt = 0; kt < 4; ++kt) {
            int k0 = kt * 32 + quad * 8;
            #pragma unroll
            for (int j = 0; j < 8; ++j) {
                short h = 0, l = 0;
                if (valid) bfsplit(W[(k0 + j) * 40 + col], h, l);
                bh[nt][kt][j] = h; blo[nt][kt][j] = l;
            }
        }
    }

    int nodeBase = tile * 16;
    const unsigned short* xrow = X + (nodeBase + ln) * 128 + quad * 8;
    sh8 a[4];
    #pragma unroll
    for (int kt = 0; kt < 4; ++kt) a[kt] = *(const sh8*)(xrow + kt * 32);

    f4 acc[3] = { {0.f,0.f,0.f,0.f}, {0.f,0.f,0.f,0.f}, {0.f,0.f,0.f,0.f} };
    #pragma unroll
    for (int kt = 0; kt < 4; ++kt)
        #pragma unroll
        for (int nt = 0; nt < 3; ++nt) {
            acc[nt] = __builtin_amdgcn_mfma_f32_16x16x32_bf16(a[kt], bh[nt][kt], acc[nt], 0, 0, 0);
            acc[nt] = __builtin_amdgcn_mfma_f32_16x16x32_bf16(a[kt], blo[nt][kt], acc[nt], 0, 0, 0);
        }

    #pragma unroll
    for (int nt = 0; nt < 3; ++nt) {
        int col = nt * 16 + ln;
        if (col < 40) {
            float bv = bl[col];
            #pragma unroll
            for (int r = 0; r < 4; ++r)
                OUT[(nodeBase + quad * 4 + r) * 40 + col] = acc[nt][r] + bv;
        }
    }
}

// ---------- launch ----------
extern "C" void kernel_launch(void* const* d_in, const int* in_sizes, int n_in,
                              void* d_out, int out_size, void* d_ws, size_t ws_size,
                              hipStream_t stream) {
    const float* x  = (const float*)d_in[0];
    const int*   ei = (const int*)d_in[1];
    const float* W1 = (const float*)d_in[2];
    const float* b1 = (const float*)d_in[3];
    const float* W2 = (const float*)d_in[4];
    const float* b2 = (const float*)d_in[5];
    const float* W3 = (const float*)d_in[6];
    const float* b3 = (const float*)d_in[7];
    const float* Wl = (const float*)d_in[8];
    const float* bl = (const float*)d_in[9];

    const int N = in_sizes[0] / 128;   // 100000
    const int E = in_sizes[1] / 2;     // 1600000
    const int* srcIdx = ei;
    const int* dstIdx = ei + E;

    char* ws = (char*)d_ws;
    size_t off = 0;
    auto alloc = [&](size_t bytes) { void* p = ws + off; off += (bytes + 511) & ~(size_t)511; return p; };
    int*   rowptr  = (int*)  alloc((size_t)N * 4);
    int*   deg     = (int*)  alloc((size_t)N * 4);
    float* dis     = (float*)alloc((size_t)N * 4);
    int*   bsum    = (int*)  alloc(512 * 4);
    unsigned short* wsp = (unsigned short*)alloc(2 * 16384 * 2);   // pre-split W1 (hi/lo)
    int*   csrc    = (int*)  alloc((size_t)E * 4);
    unsigned short* h0 = (unsigned short*)alloc((size_t)N * 128 * 2);
    unsigned short* h1 = (unsigned short*)alloc((size_t)N * 128 * 2);
    // Aliases live in h1 (h0 is written CONCURRENTLY by fused gemm1):
    //   rank (E ints, 6.4MB)  -> h1 + 0MB    (fused count -> k_fill)
    //   off8 (8N ints, 3.2MB) -> h1 + 8MB    (k_scan_a/c -> k_fill)
    //   cnt8 (8N ints, 3.2MB) -> h1 + 16MB   (k_init/fused count -> k_scan_a)
    int* rank = (int*)h1;
    int* off8 = (int*)((char*)h1 + (8u << 20));
    int* cnt8 = (int*)((char*)h1 + (16u << 20));
    unsigned short* Wh1 = wsp;
    unsigned short* Wl1 = wsp + 16384;

    const int gN = (N + 255) / 256;           // 391
    const int nPairs = N / 32;                // 3125
    const int nTiles = N / 16;                // 6250
    const int gAgg = (N * 32 + 255) / 256;    // 12500 (half-wave per node)
    const int gZ8 = (N * 8 + 255) / 256;      // zero 8N counters (covers 16384 split idx too)

    // Init (zero counters + W1 pre-split), fused(count || gemm1), scans, atomic-free fill
    k_init<<<gZ8, 256, 0, stream>>>(cnt8, N * 8, W1, wsp);
    k_count_gemm1<<<CG_BLOCKS, 256, 0, stream>>>(dstIdx, cnt8, rank, E, N,
                                                 x, Wh1, Wl1, h0, nPairs);
    k_scan_a<<<gN, 256, 0, stream>>>(cnt8, rowptr, off8, deg, bsum, dis, N);
    k_scan_b<<<1, 512, 0, stream>>>(bsum, gN);
    k_scan_c<<<gN, 256, 0, stream>>>(rowptr, off8, bsum, N);
    k_fill<<<CSR_GRID, 256, 0, stream>>>(srcIdx, dstIdx, rank, off8, csrc, E, N);

    // Layer 1 aggregation (unscaled H: gathers dis[src] per edge)
    k_agg<<<gAgg, 256, 0, stream>>>(h0, h1, dis, rowptr, deg, csrc, b1, 1, 0, N);
    // Layer 2
    k_gemm128_a16<<<768, 256, 0, stream>>>(h1, W2, dis, h0, nPairs);
    k_agg<<<gAgg, 256, 0, stream>>>(h0, h1, dis, rowptr, deg, csrc, b2, 1, 1, N);
    // Layer 3 (no relu)
    k_gemm128_a16<<<768, 256, 0, stream>>>(h1, W3, dis, h0, nPairs);
    k_agg<<<gAgg, 256, 0, stream>>>(h0, h1, dis, rowptr, deg, csrc, b3, 0, 1, N);
    // Head
    k_gemm_final<<<(nTiles + 3) / 4, 256, 0, stream>>>(h1, Wl, bl, (float*)d_out, nTiles);
}

// Round 14
// 448.721 us; speedup vs baseline: 4.9284x; 1.0470x over previous
//
#include <hip/hip_runtime.h>

// ---------- types & helpers ----------
typedef __attribute__((ext_vector_type(8))) short sh8;   // 8 x bf16 (4 VGPRs)
typedef __attribute__((ext_vector_type(4))) float f4;    // MFMA accum / float4

__device__ __forceinline__ float bf2f(unsigned short u) {
    union { unsigned int u; float f; } c; c.u = ((unsigned int)u) << 16; return c.f;
}
__device__ __forceinline__ unsigned short f2bf(float f) {
    union { float f; unsigned int u; } c; c.f = f;
    unsigned int x = c.u;
    unsigned int r = (x + 0x7fffu + ((x >> 16) & 1u)) >> 16;   // RNE
    return (unsigned short)r;
}
__device__ __forceinline__ void bfsplit(float x, short& hi, short& lo) {
    unsigned short h = f2bf(x);
    float r = x - bf2f(h);
    hi = (short)h;
    lo = (short)f2bf(r);
}

// Fused count||gemm1 sized to EXACT residency (round-11 verified: 87->76us).
#define CG_BLOCKS 1024   // even bid = count (512), odd bid = gemm (512)
#define CG_COUNT  512    // divisible by 8 -> fill reconstructs copy as (i>>8)&7
#define CSR_GRID  1568   // fill grid

// ---------- INIT: zero counters + pre-split W1 + head-const c40 = b3@Wl + bl ----------
__global__ void k_init(int* cnt8, int M,
                       const float* __restrict__ W1, unsigned short* __restrict__ sp,
                       const float* __restrict__ b3, const float* __restrict__ Wl,
                       const float* __restrict__ bl, float* __restrict__ c40) {
    int j = blockIdx.x * 256 + threadIdx.x;
    if (j < M) cnt8[j] = 0;
    if (j < 16384) {
        int k = j >> 7, col = j & 127;
        int t = col * 128 + k;
        short h, l;
        bfsplit(W1[j], h, l);
        sp[t] = (unsigned short)h;
        sp[16384 + t] = (unsigned short)l;
    }
    if (j < 40) {   // c40[col] = sum_k b3[k]*Wl[k][col] + bl[col]
        float acc = bl[j];
        for (int k = 0; k < 128; ++k) acc += b3[k] * Wl[k * 40 + j];
        c40[j] = acc;
    }
}

// ---------- FUSED: degree count (+rank emit)  ||  layer-1 GEMM (unscaled) ----------
__device__ __forceinline__ void count_body(const int* __restrict__ dst,
                                           int* __restrict__ cnt8,
                                           int* __restrict__ rank, int E, int N) {
    int cidx = blockIdx.x >> 1;
    int base = (cidx & 7) * N;
    int E4 = E >> 2;
    for (int i = cidx * 256 + threadIdx.x; i < E4; i += CG_COUNT * 256) {
        int4 d = ((const int4*)dst)[i];
        int4 r;
        r.x = ((unsigned)d.x < (unsigned)N) ? atomicAdd(&cnt8[base + d.x], 1) : -1;
        r.y = ((unsigned)d.y < (unsigned)N) ? atomicAdd(&cnt8[base + d.y], 1) : -1;
        r.z = ((unsigned)d.z < (unsigned)N) ? atomicAdd(&cnt8[base + d.z], 1) : -1;
        r.w = ((unsigned)d.w < (unsigned)N) ? atomicAdd(&cnt8[base + d.w], 1) : -1;
        ((int4*)rank)[i] = r;
    }
    if (cidx == 0) {   // remainder edges -> copy 0
        for (int e = (E4 << 2) + threadIdx.x; e < E; e += 256) {
            int d = dst[e];
            rank[e] = ((unsigned)d < (unsigned)N) ? atomicAdd(&cnt8[d], 1) : -1;
        }
    }
}

// H[N][128](bf16) = X[N][128](fp32) @ W1 (unscaled; agg1 applies dis[src]).
__device__ __forceinline__ void gemm1_body(const float* __restrict__ X,
                                           const unsigned short* __restrict__ Wh,
                                           const unsigned short* __restrict__ Wl,
                                           unsigned short* __restrict__ H, int nPairs) {
    int gidx = blockIdx.x >> 1;
    int wave = threadIdx.x >> 6;
    int lane = threadIdx.x & 63;
    int ln = lane & 15, quad = lane >> 4;
    int c0 = (wave & 1) * 64;
    int subTile = wave >> 1;

    for (int p = gidx; p < nPairs; p += CG_COUNT) {
        int nodeBase = p * 32 + subTile * 16;
        const float* xrow = X + (nodeBase + ln) * 128 + quad * 8;
        sh8 ah[4], al[4];
        #pragma unroll
        for (int kt = 0; kt < 4; ++kt) {
            f4 v0 = *(const f4*)(xrow + kt * 32);
            f4 v1 = *(const f4*)(xrow + kt * 32 + 4);
            #pragma unroll
            for (int j = 0; j < 4; ++j) {
                short h, l;
                bfsplit(v0[j], h, l); ah[kt][j] = h; al[kt][j] = l;
                bfsplit(v1[j], h, l); ah[kt][j + 4] = h; al[kt][j + 4] = l;
            }
        }

        f4 acc[4] = { {0.f,0.f,0.f,0.f}, {0.f,0.f,0.f,0.f}, {0.f,0.f,0.f,0.f}, {0.f,0.f,0.f,0.f} };
        #pragma unroll
        for (int kt = 0; kt < 4; ++kt) {
            int k0 = kt * 32 + quad * 8;
            #pragma unroll
            for (int nt = 0; nt < 4; ++nt) {
                int col = c0 + nt * 16 + ln;
                sh8 bh = *(const sh8*)(Wh + col * 128 + k0);
                sh8 bl = *(const sh8*)(Wl + col * 128 + k0);
                acc[nt] = __builtin_amdgcn_mfma_f32_16x16x32_bf16(ah[kt], bh, acc[nt], 0, 0, 0);
                acc[nt] = __builtin_amdgcn_mfma_f32_16x16x32_bf16(ah[kt], bl, acc[nt], 0, 0, 0);
                acc[nt] = __builtin_amdgcn_mfma_f32_16x16x32_bf16(al[kt], bh, acc[nt], 0, 0, 0);
            }
        }

        #pragma unroll
        for (int nt = 0; nt < 4; ++nt) {
            int col = c0 + nt * 16 + ln;
            #pragma unroll
            for (int r = 0; r < 4; ++r)
                H[(nodeBase + quad * 4 + r) * 128 + col] = f2bf(acc[nt][r]);
        }
    }
}

__global__ __launch_bounds__(256)
void k_count_gemm1(const int* __restrict__ dst, int* __restrict__ cnt8,
                   int* __restrict__ rank, int E, int N,
                   const float* __restrict__ X,
                   const unsigned short* __restrict__ Wh,
                   const unsigned short* __restrict__ Wl,
                   unsigned short* __restrict__ H, int nPairs) {
    if ((blockIdx.x & 1) == 0)
        count_body(dst, cnt8, rank, E, N);
    else
        gemm1_body(X, Wh, Wl, H, nPairs);
}

#define SCAN_B 256
__global__ void k_scan_a(const int* __restrict__ cnt8, int* __restrict__ rowptr,
                         int* __restrict__ off8, int* __restrict__ deg,
                         int* __restrict__ bsum, float* __restrict__ dis, int N) {
    __shared__ int sh[SCAN_B];
    int t = threadIdx.x, i = blockIdx.x * SCAN_B + t;
    int c[8];
    int v = 0;
    if (i < N) {
        #pragma unroll
        for (int g = 0; g < 8; ++g) { c[g] = cnt8[g * N + i]; v += c[g]; }
        dis[i] = rsqrtf((float)(v + 1));   // +1 self loop
        deg[i] = v;
    }
    sh[t] = v; __syncthreads();
    for (int off = 1; off < SCAN_B; off <<= 1) {
        int x = (t >= off) ? sh[t - off] : 0;
        __syncthreads();
        sh[t] += x;
        __syncthreads();
    }
    int incl = sh[t];
    if (i < N) {
        int b = incl - v;
        rowptr[i] = b;
        int o = b;
        #pragma unroll
        for (int g = 0; g < 8; ++g) { off8[g * N + i] = o; o += c[g]; }
    }
    if (t == SCAN_B - 1) bsum[blockIdx.x] = incl;
}

__global__ void k_scan_b(int* bsum, int NB) {
    __shared__ int sh[512];
    int t = threadIdx.x;
    int v = (t < NB) ? bsum[t] : 0;
    sh[t] = v; __syncthreads();
    for (int off = 1; off < 512; off <<= 1) {
        int x = (t >= off) ? sh[t - off] : 0;
        __syncthreads();
        sh[t] += x;
        __syncthreads();
    }
    if (t < NB) bsum[t] = sh[t] - v;
}

__global__ void k_scan_c(int* __restrict__ rowptr, int* __restrict__ off8,
                         const int* __restrict__ bsum, int N) {
    int i = blockIdx.x * 256 + threadIdx.x;
    if (i < N) {
        int b = bsum[blockIdx.x];
        rowptr[i] += b;
        #pragma unroll
        for (int g = 0; g < 8; ++g) off8[g * N + i] += b;
    }
}

// ---------- Atomic-free CSR fill ----------
__global__ void k_fill(const int* __restrict__ src, const int* __restrict__ dst,
                       const int* __restrict__ rank, const int* __restrict__ off8,
                       int* __restrict__ csrc, int E, int N) {
    int E4 = E >> 2;
    for (int i = blockIdx.x * 256 + threadIdx.x; i < E4; i += gridDim.x * 256) {
        int g = (i >> 8) & 7;
        const int* off = off8 + g * N;
        int4 d4 = ((const int4*)dst)[i];
        int4 s4 = ((const int4*)src)[i];
        int4 r4 = ((const int4*)rank)[i];
        #pragma unroll
        for (int q = 0; q < 4; ++q) {
            int d = (q == 0) ? d4.x : (q == 1) ? d4.y : (q == 2) ? d4.z : d4.w;
            int s = (q == 0) ? s4.x : (q == 1) ? s4.y : (q == 2) ? s4.z : s4.w;
            int r = (q == 0) ? r4.x : (q == 1) ? r4.y : (q == 2) ? r4.z : r4.w;
            if ((unsigned)d >= (unsigned)N || (unsigned)s >= (unsigned)N || r < 0) continue;
            csrc[off[d] + r] = s;
        }
    }
    if (blockIdx.x == 0) {   // remainder edges -> copy 0
        for (int e = (E4 << 2) + threadIdx.x; e < E; e += 256) {
            int d = dst[e];
            int s = src[e];
            int r = rank[e];
            if ((unsigned)d >= (unsigned)N || (unsigned)s >= (unsigned)N || r < 0) continue;
            csrc[off8[d] + r] = s;
        }
    }
}

// ---------- GEMM (layers 2,3): reg-cached split W + 1-deep A prefetch ----------
__global__ __launch_bounds__(256)
void k_gemm128_a16(const unsigned short* __restrict__ X,
                   const float* __restrict__ W,
                   const float* __restrict__ dis,
                   unsigned short* __restrict__ H, int nPairs) {
    int wave = threadIdx.x >> 6;
    int lane = threadIdx.x & 63;
    int ln = lane & 15, quad = lane >> 4;
    int c0 = (wave & 1) * 64;
    int subTile = wave >> 1;

    sh8 bh[4][4], blo[4][4];
    #pragma unroll
    for (int nt = 0; nt < 4; ++nt) {
        int col = c0 + nt * 16 + ln;
        #pragma unroll
        for (int kt = 0; kt < 4; ++kt) {
            int k0 = kt * 32 + quad * 8;
            #pragma unroll
            for (int j = 0; j < 8; ++j) {
                short h, l;
                bfsplit(W[(k0 + j) * 128 + col], h, l);
                bh[nt][kt][j] = h; blo[nt][kt][j] = l;
            }
        }
    }

    int p = blockIdx.x;
    sh8 a[4];
    if (p < nPairs) {
        const unsigned short* xrow = X + ((size_t)(p * 32 + subTile * 16 + ln)) * 128 + quad * 8;
        #pragma unroll
        for (int kt = 0; kt < 4; ++kt) a[kt] = *(const sh8*)(xrow + kt * 32);
    }
    while (p < nPairs) {
        int pn = p + (int)gridDim.x;
        sh8 an[4];
        if (pn < nPairs) {   // prefetch next tile's A before current MFMAs
            const unsigned short* xn = X + ((size_t)(pn * 32 + subTile * 16 + ln)) * 128 + quad * 8;
            #pragma unroll
            for (int kt = 0; kt < 4; ++kt) an[kt] = *(const sh8*)(xn + kt * 32);
        }

        f4 acc[4] = { {0.f,0.f,0.f,0.f}, {0.f,0.f,0.f,0.f}, {0.f,0.f,0.f,0.f}, {0.f,0.f,0.f,0.f} };
        #pragma unroll
        for (int kt = 0; kt < 4; ++kt)
            #pragma unroll
            for (int nt = 0; nt < 4; ++nt) {
                acc[nt] = __builtin_amdgcn_mfma_f32_16x16x32_bf16(a[kt], bh[nt][kt], acc[nt], 0, 0, 0);
                acc[nt] = __builtin_amdgcn_mfma_f32_16x16x32_bf16(a[kt], blo[nt][kt], acc[nt], 0, 0, 0);
            }

        int nodeBase = p * 32 + subTile * 16;
        float ds[4];
        #pragma unroll
        for (int r = 0; r < 4; ++r) ds[r] = dis[nodeBase + quad * 4 + r];
        #pragma unroll
        for (int nt = 0; nt < 4; ++nt) {
            int col = c0 + nt * 16 + ln;
            #pragma unroll
            for (int r = 0; r < 4; ++r)
                H[(nodeBase + quad * 4 + r) * 128 + col] = f2bf(acc[nt][r] * ds[r]);
        }

        #pragma unroll
        for (int kt = 0; kt < 4; ++kt) a[kt] = an[kt];
        p = pn;
    }
}

// ---------- Aggregation (layers 1,2): one HALF-WAVE (2 x 16 lanes) per node ----------
__global__ __launch_bounds__(256)
void k_agg(const unsigned short* __restrict__ H,
           unsigned short* __restrict__ O,
           const float* __restrict__ dis,
           const int* __restrict__ rowptr,
           const int* __restrict__ deg,
           const int* __restrict__ csrc,
           const float* __restrict__ bias,
           int relu, int scaled, int N) {
    int n = (blockIdx.x * 256 + threadIdx.x) >> 5;
    if (n >= N) return;
    int lane = threadIdx.x & 31;
    int sub  = lane & 15;      // feats sub*8 .. sub*8+7 (16B)
    int half = lane >> 4;      // which edge of each pair

    float a0 = 0.f, a1 = 0.f, a2 = 0.f, a3 = 0.f;
    float a4 = 0.f, a5 = 0.f, a6 = 0.f, a7 = 0.f;
    float dn = dis[n];

    auto addrow = [&](uint4 v) {
        a0 += bf2f((unsigned short)v.x);
        a1 += bf2f((unsigned short)(v.x >> 16));
        a2 += bf2f((unsigned short)v.y);
        a3 += bf2f((unsigned short)(v.y >> 16));
        a4 += bf2f((unsigned short)v.z);
        a5 += bf2f((unsigned short)(v.z >> 16));
        a6 += bf2f((unsigned short)v.w);
        a7 += bf2f((unsigned short)(v.w >> 16));
    };
    auto addroww = [&](uint4 v, float w) {
        a0 = fmaf(w, bf2f((unsigned short)v.x), a0);
        a1 = fmaf(w, bf2f((unsigned short)(v.x >> 16)), a1);
        a2 = fmaf(w, bf2f((unsigned short)v.y), a2);
        a3 = fmaf(w, bf2f((unsigned short)(v.y >> 16)), a3);
        a4 = fmaf(w, bf2f((unsigned short)v.z), a4);
        a5 = fmaf(w, bf2f((unsigned short)(v.z >> 16)), a5);
        a6 = fmaf(w, bf2f((unsigned short)v.w), a6);
        a7 = fmaf(w, bf2f((unsigned short)(v.w >> 16)), a7);
    };

    if (half == 0) {   // self loop (final *dn gives dn^2 weight)
        uint4 v = *(const uint4*)(H + (size_t)n * 128 + sub * 8);
        if (scaled) addrow(v); else addroww(v, dn);
    }

    int start = rowptr[n];
    int e = deg[n];
    int i = 0;
    if (scaled) {
        for (; i + 8 <= e; i += 8) {     // 8 edges per round, 4 per 16-lane group
            int s[4];
            #pragma unroll
            for (int q = 0; q < 4; ++q) s[q] = csrc[start + i + 2 * q + half];
            uint4 v[4];
            #pragma unroll
            for (int q = 0; q < 4; ++q) v[q] = *(const uint4*)(H + (size_t)s[q] * 128 + sub * 8);
            #pragma unroll
            for (int q = 0; q < 4; ++q) addrow(v[q]);
        }
        for (int j = i + half; j < e; j += 2) {
            int s = csrc[start + j];
            addrow(*(const uint4*)(H + (size_t)s * 128 + sub * 8));
        }
    } else {
        for (; i + 8 <= e; i += 8) {
            int s[4];
            #pragma unroll
            for (int q = 0; q < 4; ++q) s[q] = csrc[start + i + 2 * q + half];
            uint4 v[4];
            #pragma unroll
            for (int q = 0; q < 4; ++q) v[q] = *(const uint4*)(H + (size_t)s[q] * 128 + sub * 8);
            float w[4];
            #pragma unroll
            for (int q = 0; q < 4; ++q) w[q] = dis[s[q]];
            #pragma unroll
            for (int q = 0; q < 4; ++q) addroww(v[q], w[q]);
        }
        for (int j = i + half; j < e; j += 2) {
            int s = csrc[start + j];
            float w = dis[s];
            addroww(*(const uint4*)(H + (size_t)s * 128 + sub * 8), w);
        }
    }

    a0 += __shfl_xor(a0, 16); a1 += __shfl_xor(a1, 16);
    a2 += __shfl_xor(a2, 16); a3 += __shfl_xor(a3, 16);
    a4 += __shfl_xor(a4, 16); a5 += __shfl_xor(a5, 16);
    a6 += __shfl_xor(a6, 16); a7 += __shfl_xor(a7, 16);

    if (half == 0) {
        f4 b0 = *(const f4*)(bias + sub * 8);
        f4 b1 = *(const f4*)(bias + sub * 8 + 4);
        a0 = a0 * dn + b0[0]; a1 = a1 * dn + b0[1];
        a2 = a2 * dn + b0[2]; a3 = a3 * dn + b0[3];
        a4 = a4 * dn + b1[0]; a5 = a5 * dn + b1[1];
        a6 = a6 * dn + b1[2]; a7 = a7 * dn + b1[3];
        if (relu) {
            a0 = fmaxf(a0, 0.f); a1 = fmaxf(a1, 0.f);
            a2 = fmaxf(a2, 0.f); a3 = fmaxf(a3, 0.f);
            a4 = fmaxf(a4, 0.f); a5 = fmaxf(a5, 0.f);
            a6 = fmaxf(a6, 0.f); a7 = fmaxf(a7, 0.f);
        }
        uint4 ov;
        ov.x = (unsigned int)f2bf(a0) | ((unsigned int)f2bf(a1) << 16);
        ov.y = (unsigned int)f2bf(a2) | ((unsigned int)f2bf(a3) << 16);
        ov.z = (unsigned int)f2bf(a4) | ((unsigned int)f2bf(a5) << 16);
        ov.w = (unsigned int)f2bf(a6) | ((unsigned int)f2bf(a7) << 16);
        *(uint4*)(O + (size_t)n * 128 + sub * 8) = ov;
    }
}

// ---------- Head-first GEMM: G[N][64](bf16, cols 40+ zero) = X(bf16 h3) @ Wl(split) ----------
// Layer 3 has NO relu -> the linear head commutes with aggregation. Applying it
// BEFORE agg3 shrinks the gather row 256B -> 128B (2x agg traffic, 2x L2 hit rate).
__global__ __launch_bounds__(256)
void k_gemm_head(const unsigned short* __restrict__ X,
                 const float* __restrict__ W,     // [128][40]
                 unsigned short* __restrict__ G,  // [N][64]
                 int nTiles) {
    int wave = threadIdx.x >> 6;
    int lane = threadIdx.x & 63;
    int ln = lane & 15, quad = lane >> 4;
    int tile = blockIdx.x * 4 + wave;
    if (tile >= nTiles) return;

    sh8 bh[3][4], blo[3][4];
    #pragma unroll
    for (int nt = 0; nt < 3; ++nt) {
        int col = nt * 16 + ln;
        bool valid = (col < 40);
        #pragma unroll
        for (int kt = 0; kt < 4; ++kt) {
            int k0 = kt * 32 + quad * 8;
            #pragma unroll
            for (int j = 0; j < 8; ++j) {
                short h = 0, l = 0;
                if (valid) bfsplit(W[(k0 + j) * 40 + col], h, l);
                bh[nt][kt][j] = h; blo[nt][kt][j] = l;
            }
        }
    }

    int nodeBase = tile * 16;
    const unsigned short* xrow = X + (nodeBase + ln) * 128 + quad * 8;
    sh8 a[4];
    #pragma unroll
    for (int kt = 0; kt < 4; ++kt) a[kt] = *(const sh8*)(xrow + kt * 32);

    f4 acc[3] = { {0.f,0.f,0.f,0.f}, {0.f,0.f,0.f,0.f}, {0.f,0.f,0.f,0.f} };
    #pragma unroll
    for (int kt = 0; kt < 4; ++kt)
        #pragma unroll
        for (int nt = 0; nt < 3; ++nt) {
            acc[nt] = __builtin_amdgcn_mfma_f32_16x16x32_bf16(a[kt], bh[nt][kt], acc[nt], 0, 0, 0);
            acc[nt] = __builtin_amdgcn_mfma_f32_16x16x32_bf16(a[kt], blo[nt][kt], acc[nt], 0, 0, 0);
        }

    #pragma unroll
    for (int nt = 0; nt < 4; ++nt) {     // nt=3 + col>=40: zero-fill the pad
        int col = nt * 16 + ln;
        #pragma unroll
        for (int r = 0; r < 4; ++r) {
            unsigned short v = 0;
            if (nt < 3 && col < 40) v = f2bf(acc[nt][r]);
            G[(size_t)(nodeBase + quad * 4 + r) * 64 + col] = v;
        }
    }
}

// ---------- 40-dim aggregation -> OUT: one 16-LANE group (2 x 8 lanes) per node ----------
// out[n] = dn * (sum_s g[s] + g[n]) + c40  (g rows pre-scaled by dis[src] via h3)
__global__ __launch_bounds__(256)
void k_agg40(const unsigned short* __restrict__ G,   // [N][64] bf16 (cols 40+ zero)
             float* __restrict__ OUT,                 // [N][40] fp32
             const float* __restrict__ dis,
             const int* __restrict__ rowptr,
             const int* __restrict__ deg,
             const int* __restrict__ csrc,
             const float* __restrict__ c40,
             int N) {
    int n = (blockIdx.x * 256 + threadIdx.x) >> 4;
    if (n >= N) return;
    int lane = threadIdx.x & 15;
    int sub  = lane & 7;       // feats sub*8 .. sub*8+7 (16B)
    int half = lane >> 3;      // which edge of each pair

    float a0 = 0.f, a1 = 0.f, a2 = 0.f, a3 = 0.f;
    float a4 = 0.f, a5 = 0.f, a6 = 0.f, a7 = 0.f;

    auto addrow = [&](uint4 v) {
        a0 += bf2f((unsigned short)v.x);
        a1 += bf2f((unsigned short)(v.x >> 16));
        a2 += bf2f((unsigned short)v.y);
        a3 += bf2f((unsigned short)(v.y >> 16));
        a4 += bf2f((unsigned short)v.z);
        a5 += bf2f((unsigned short)(v.z >> 16));
        a6 += bf2f((unsigned short)v.w);
        a7 += bf2f((unsigned short)(v.w >> 16));
    };

    if (half == 0)   // self loop
        addrow(*(const uint4*)(G + (size_t)n * 64 + sub * 8));

    int start = rowptr[n];
    int e = deg[n];
    int i = 0;
    for (; i + 8 <= e; i += 8) {   // 8 edges per round, 4 per 8-lane subgroup
        int s[4];
        #pragma unroll
        for (int q = 0; q < 4; ++q) s[q] = csrc[start + i + 2 * q + half];
        uint4 v[4];
        #pragma unroll
        for (int q = 0; q < 4; ++q) v[q] = *(const uint4*)(G + (size_t)s[q] * 64 + sub * 8);
        #pragma unroll
        for (int q = 0; q < 4; ++q) addrow(v[q]);
    }
    for (int j = i + half; j < e; j += 2) {
        int s = csrc[start + j];
        addrow(*(const uint4*)(G + (size_t)s * 64 + sub * 8));
    }

    a0 += __shfl_xor(a0, 8); a1 += __shfl_xor(a1, 8);
    a2 += __shfl_xor(a2, 8); a3 += __shfl_xor(a3, 8);
    a4 += __shfl_xor(a4, 8); a5 += __shfl_xor(a5, 8);
    a6 += __shfl_xor(a6, 8); a7 += __shfl_xor(a7, 8);

    if (half == 0 && sub < 5) {   // cols sub*8 .. sub*8+7 (0..39)
        float dn = dis[n];
        int col0 = sub * 8;
        const float* c = c40 + col0;
        f4 o0, o1;
        o0[0] = a0 * dn + c[0]; o0[1] = a1 * dn + c[1];
        o0[2] = a2 * dn + c[2]; o0[3] = a3 * dn + c[3];
        o1[0] = a4 * dn + c[4]; o1[1] = a5 * dn + c[5];
        o1[2] = a6 * dn + c[6]; o1[3] = a7 * dn + c[7];
        float* dst = OUT + (size_t)n * 40 + col0;
        *(f4*)dst = o0;
        *(f4*)(dst + 4) = o1;
    }
}

// ---------- launch ----------
extern "C" void kernel_launch(void* const* d_in, const int* in_sizes, int n_in,
                              void* d_out, int out_size, void* d_ws, size_t ws_size,
                              hipStream_t stream) {
    const float* x  = (const float*)d_in[0];
    const int*   ei = (const int*)d_in[1];
    const float* W1 = (const float*)d_in[2];
    const float* b1 = (const float*)d_in[3];
    const float* W2 = (const float*)d_in[4];
    const float* b2 = (const float*)d_in[5];
    const float* W3 = (const float*)d_in[6];
    const float* b3 = (const float*)d_in[7];
    const float* Wl = (const float*)d_in[8];
    const float* bl = (const float*)d_in[9];

    const int N = in_sizes[0] / 128;   // 100000
    const int E = in_sizes[1] / 2;     // 1600000
    const int* srcIdx = ei;
    const int* dstIdx = ei + E;

    char* ws = (char*)d_ws;
    size_t off = 0;
    auto alloc = [&](size_t bytes) { void* p = ws + off; off += (bytes + 511) & ~(size_t)511; return p; };
    int*   rowptr  = (int*)  alloc((size_t)N * 4);
    int*   deg     = (int*)  alloc((size_t)N * 4);
    float* dis     = (float*)alloc((size_t)N * 4);
    int*   bsum    = (int*)  alloc(512 * 4);
    float* c40     = (float*)alloc(64 * 4);
    unsigned short* wsp = (unsigned short*)alloc(2 * 16384 * 2);   // pre-split W1 (hi/lo)
    int*   csrc    = (int*)  alloc((size_t)E * 4);
    unsigned short* h0 = (unsigned short*)alloc((size_t)N * 128 * 2);
    unsigned short* h1 = (unsigned short*)alloc((size_t)N * 128 * 2);
    // Aliases live in h1 (h0 is written CONCURRENTLY by fused gemm1):
    //   rank (E ints, 6.4MB)  -> h1 + 0MB    (fused count -> k_fill)
    //   off8 (8N ints, 3.2MB) -> h1 + 8MB    (k_scan_a/c -> k_fill)
    //   cnt8 (8N ints, 3.2MB) -> h1 + 16MB   (k_init/fused count -> k_scan_a)
    int* rank = (int*)h1;
    int* off8 = (int*)((char*)h1 + (8u << 20));
    int* cnt8 = (int*)((char*)h1 + (16u << 20));
    unsigned short* Wh1 = wsp;
    unsigned short* Wl1 = wsp + 16384;
    unsigned short* g64 = h1;   // head output [N][64] bf16 (h1 free after gemm3 reads it)

    const int gN = (N + 255) / 256;           // 391
    const int nPairs = N / 32;                // 3125
    const int nTiles = N / 16;                // 6250
    const int gAgg = (N * 32 + 255) / 256;    // 12500 (half-wave per node)
    const int gA40 = (N * 16 + 255) / 256;    // 6250 (16-lane group per node)
    const int gZ8 = (N * 8 + 255) / 256;

    // Init (counters + W1 pre-split + c40), fused(count || gemm1), scans, atomic-free fill
    k_init<<<gZ8, 256, 0, stream>>>(cnt8, N * 8, W1, wsp, b3, Wl, bl, c40);
    k_count_gemm1<<<CG_BLOCKS, 256, 0, stream>>>(dstIdx, cnt8, rank, E, N,
                                                 x, Wh1, Wl1, h0, nPairs);
    k_scan_a<<<gN, 256, 0, stream>>>(cnt8, rowptr, off8, deg, bsum, dis, N);
    k_scan_b<<<1, 512, 0, stream>>>(bsum, gN);
    k_scan_c<<<gN, 256, 0, stream>>>(rowptr, off8, bsum, N);
    k_fill<<<CSR_GRID, 256, 0, stream>>>(srcIdx, dstIdx, rank, off8, csrc, E, N);

    // Layer 1 aggregation (unscaled H: gathers dis[src] per edge)
    k_agg<<<gAgg, 256, 0, stream>>>(h0, h1, dis, rowptr, deg, csrc, b1, 1, 0, N);
    // Layer 2
    k_gemm128_a16<<<768, 256, 0, stream>>>(h1, W2, dis, h0, nPairs);
    k_agg<<<gAgg, 256, 0, stream>>>(h0, h1, dis, rowptr, deg, csrc, b2, 1, 1, N);
    // Layer 3 (no relu): gemm3 -> h0 (pre-scaled rows)
    k_gemm128_a16<<<768, 256, 0, stream>>>(h1, W3, dis, h0, nPairs);
    // Head FIRST (linearity: no relu in layer 3), then 40-dim aggregation -> OUT
    k_gemm_head<<<(nTiles + 3) / 4, 256, 0, stream>>>(h0, Wl, g64, nTiles);
    k_agg40<<<gA40, 256, 0, stream>>>(g64, (float*)d_out, dis, rowptr, deg, csrc, c40, N);
}